// Round 4
// baseline (366.399 us; speedup 1.0000x reference)
//
#include <hip/hip_runtime.h>

#define V 128
#define D 20
#define NUM_EMB (V * V * V)

typedef float v4f __attribute__((ext_vector_type(4)));

// 5 threads per point, 2 points per thread: thread (lp,k) handles float4
// chunk k of points i0 = blk*128+lp and i1 = i0+64. 16 independent 16B
// gathers in flight per thread (MLP 2x vs round 3) to attack gather latency.
__global__ __launch_bounds__(320) void dense_grid_enc_kernel(
    const float* __restrict__ x, const float* __restrict__ grid,
    float* __restrict__ out, int N)
{
    int tid = threadIdx.x;            // 0..319
    int lp  = tid / 5;                // local point 0..63
    int k   = tid - lp * 5;           // chunk 0..4
    int i0  = blockIdx.x * 128 + lp;  // first point
    int i1  = i0 + 64;                // second point

    bool v0 = (i0 < N);
    bool v1 = (i1 < N);
    if (!v0) return;

    // safe index for inactive second point (re-reads point i0; result discarded)
    int i1s = v1 ? i1 : i0;

    float px0 = x[3 * i0 + 0], py0 = x[3 * i0 + 1], pz0 = x[3 * i0 + 2];
    float px1 = x[3 * i1s + 0], py1 = x[3 * i1s + 1], pz1 = x[3 * i1s + 2];

    // ---- point 0 indices/weights ----
    int ix0 = (int)floorf((px0 + 1.0f) * 64.0f);
    int iy0 = (int)floorf((py0 + 1.0f) * 64.0f);
    int iz0 = (int)floorf((pz0 + 1.0f) * 64.0f);
    float wx1_0 = (px0 - ((float)ix0 * (2.0f/128.0f) - 1.0f)) * 64.0f;
    float wx0_0 = (((float)(ix0+1) * (2.0f/128.0f) - 1.0f) - px0) * 64.0f;
    float wy1_0 = (py0 - ((float)iy0 * (2.0f/128.0f) - 1.0f)) * 64.0f;
    float wy0_0 = (((float)(iy0+1) * (2.0f/128.0f) - 1.0f) - py0) * 64.0f;
    float wz1_0 = (pz0 - ((float)iz0 * (2.0f/128.0f) - 1.0f)) * 64.0f;
    float wz0_0 = (((float)(iz0+1) * (2.0f/128.0f) - 1.0f) - pz0) * 64.0f;
    int f0 = ix0 + iy0 * V + iz0 * V * V;

    // ---- point 1 indices/weights ----
    int ix1 = (int)floorf((px1 + 1.0f) * 64.0f);
    int iy1 = (int)floorf((py1 + 1.0f) * 64.0f);
    int iz1 = (int)floorf((pz1 + 1.0f) * 64.0f);
    float wx1_1 = (px1 - ((float)ix1 * (2.0f/128.0f) - 1.0f)) * 64.0f;
    float wx0_1 = (((float)(ix1+1) * (2.0f/128.0f) - 1.0f) - px1) * 64.0f;
    float wy1_1 = (py1 - ((float)iy1 * (2.0f/128.0f) - 1.0f)) * 64.0f;
    float wy0_1 = (((float)(iy1+1) * (2.0f/128.0f) - 1.0f) - py1) * 64.0f;
    float wz1_1 = (pz1 - ((float)iz1 * (2.0f/128.0f) - 1.0f)) * 64.0f;
    float wz0_1 = (((float)(iz1+1) * (2.0f/128.0f) - 1.0f) - pz1) * 64.0f;
    int f1 = ix1 + iy1 * V + iz1 * V * V;

    const int doff[8] = {0, 1, V, V + 1, V*V, V*V + 1, V*V + V, V*V + V + 1};

    int fl0[8], fl1[8];
    #pragma unroll
    for (int c = 0; c < 8; c++) {
        int a = f0 + doff[c]; if (a > NUM_EMB - 1) a = NUM_EMB - 1;
        int b = f1 + doff[c]; if (b > NUM_EMB - 1) b = NUM_EMB - 1;
        fl0[c] = a; fl1[c] = b;
    }

    // ---- issue all 16 gathers before any use ----
    v4f q0[8], q1[8];
    #pragma unroll
    for (int c = 0; c < 8; c++)
        q0[c] = *(const v4f*)(grid + (size_t)fl0[c] * D + 4 * k);
    #pragma unroll
    for (int c = 0; c < 8; c++)
        q1[c] = *(const v4f*)(grid + (size_t)fl1[c] * D + 4 * k);

    float w0[8], w1[8];
    w0[0] = wx0_0 * wy0_0 * wz0_0;  w1[0] = wx0_1 * wy0_1 * wz0_1;
    w0[1] = wx1_0 * wy0_0 * wz0_0;  w1[1] = wx1_1 * wy0_1 * wz0_1;
    w0[2] = wx0_0 * wy1_0 * wz0_0;  w1[2] = wx0_1 * wy1_1 * wz0_1;
    w0[3] = wx1_0 * wy1_0 * wz0_0;  w1[3] = wx1_1 * wy1_1 * wz0_1;
    w0[4] = wx0_0 * wy0_0 * wz1_0;  w1[4] = wx0_1 * wy0_1 * wz1_1;
    w0[5] = wx1_0 * wy0_0 * wz1_0;  w1[5] = wx1_1 * wy0_1 * wz1_1;
    w0[6] = wx0_0 * wy1_0 * wz1_0;  w1[6] = wx0_1 * wy1_1 * wz1_1;
    w0[7] = wx1_0 * wy1_0 * wz1_0;  w1[7] = wx1_1 * wy1_1 * wz1_1;

    v4f acc0 = (v4f)(0.0f), acc1 = (v4f)(0.0f);
    #pragma unroll
    for (int c = 0; c < 8; c++) { acc0 += w0[c] * q0[c]; acc1 += w1[c] * q1[c]; }

    __builtin_nontemporal_store(acc0, (v4f*)(out + (size_t)i0 * D + 4 * k));
    if (v1)
        __builtin_nontemporal_store(acc1, (v4f*)(out + (size_t)i1 * D + 4 * k));
}

extern "C" void kernel_launch(void* const* d_in, const int* in_sizes, int n_in,
                              void* d_out, int out_size, void* d_ws, size_t ws_size,
                              hipStream_t stream) {
    const float* x = (const float*)d_in[0];
    const float* grid = (const float*)d_in[1];
    float* out = (float*)d_out;
    int N = in_sizes[0] / 3;

    int pts_per_block = 128;
    int nblocks = (N + pts_per_block - 1) / pts_per_block;
    dense_grid_enc_kernel<<<nblocks, 320, 0, stream>>>(x, grid, out, N);
}